// Round 4
// baseline (466.041 us; speedup 1.0000x reference)
//
#include <hip/hip_runtime.h>

#define N_NODES 100000
#define N_EDGES 1200000

#define BIN_SHIFT 6
#define NODES_PER_BIN 64                       // 1 << BIN_SHIFT
#define NBINS ((N_NODES + NODES_PER_BIN - 1) >> BIN_SHIFT)   // 1563
#define CAP 1024                               // max edges per bucket (mean 768)
#define EPB 8192                               // edges per binning block
#define NBLK_BIN ((N_EDGES + EPB - 1) / EPB)   // 147

// ---------------- zero int ----------------
__global__ void zero_int_kernel(int* __restrict__ p, int n) {
    int i = blockIdx.x * blockDim.x + threadIdx.x;
    if (i < n) p[i] = 0;
}

// ---------------- binning: edges -> fixed-stride bucket regions ----------------
// packed word: src (bits 0..16) | (dst & 63) << 17
__global__ void binning_kernel(const int* __restrict__ src, const int* __restrict__ dst,
                               int* __restrict__ gcursor, unsigned int* __restrict__ binned,
                               int E) {
    __shared__ unsigned int stage[EPB];      // 32 KB
    __shared__ unsigned short sbin[EPB];     // 16 KB
    __shared__ unsigned int hist[NBINS];     // ~6.3 KB
    int t = threadIdx.x;
    int e_base = blockIdx.x * EPB;

    for (int b = t; b < NBINS; b += 256) hist[b] = 0;
    __syncthreads();

#pragma unroll
    for (int j = 0; j < EPB / 256; ++j) {
        int idx = e_base + t + j * 256;
        if (idx < E) {
            int s = src[idx];
            int d = dst[idx];
            unsigned int bin = (unsigned int)d >> BIN_SHIFT;
            unsigned int p = (unsigned int)s | (((unsigned int)d & 63u) << 17);
            stage[t + j * 256] = p;
            sbin[t + j * 256] = (unsigned short)bin;
            atomicAdd(&hist[bin], 1u);
        }
    }
    __syncthreads();

    for (int b = t; b < NBINS; b += 256) {
        unsigned int c = hist[b];
        if (c) hist[b] = (unsigned int)(b * CAP) + (unsigned int)atomicAdd(&gcursor[b], (int)c);
    }
    __syncthreads();

#pragma unroll
    for (int j = 0; j < EPB / 256; ++j) {
        int idx = e_base + t + j * 256;
        if (idx < E) {
            unsigned int bin = sbin[t + j * 256];
            unsigned int pos = atomicAdd(&hist[bin], 1u);
            binned[pos] = stage[t + j * 256];
        }
    }
}

// ---------------- dinv: per-bucket local degree count -> rsqrt(deg+1) ----------------
__global__ void dinv_kernel(const unsigned int* __restrict__ binned,
                            const int* __restrict__ gcursor,
                            float* __restrict__ dinv) {
    __shared__ unsigned int counts[NODES_PER_BIN];
    int bin = blockIdx.x;
    int t = threadIdx.x;
    if (t < NODES_PER_BIN) counts[t] = 0;
    __syncthreads();
    int nb = gcursor[bin];
    const unsigned int* eb = binned + (size_t)bin * CAP;
    for (int i = t; i < nb; i += 256) atomicAdd(&counts[eb[i] >> 17], 1u);
    __syncthreads();
    if (t < NODES_PER_BIN) {
        int node = bin * NODES_PER_BIN + t;
        if (node < N_NODES) dinv[node] = rsqrtf((float)(counts[t] + 1u));
    }
}

// ---------------- register-tiled skinny GEMM ----------------
// H[n,DOUT] = rowscale[r] * (X[n,64] @ W[64,DOUT]) (+bias)
// 256 threads, 128 rows/block. Thread (rg,cg): rows rg+RGS*r, cols 4*cg..4*cg+3.
// All LDS traffic is ds_read_b128; sX padded to 17 float4/row for bank-disjoint row reads.
template<int DOUT>
__global__ __launch_bounds__(256) void gemm_kernel(const float* __restrict__ X,
                                                   const float* __restrict__ W,
                                                   const float* __restrict__ bias,
                                                   const float* __restrict__ rowscale,
                                                   float* __restrict__ H, int n) {
    constexpr int COLG = DOUT / 4;       // 16 or 8 float4 col-groups
    constexpr int RGS  = 256 / COLG;     // 16 or 32 row-groups
    constexpr int RPT  = 128 / RGS;      // 8 or 4 rows per thread
    constexpr int XPITCH = 17;           // float4 pitch (68 floats)
    __shared__ float4 sW4[64 * COLG];
    __shared__ float4 sX4[128 * XPITCH];
    int tid = threadIdx.x;

    for (int i = tid; i < 64 * COLG; i += 256) sW4[i] = ((const float4*)W)[i];

    int base_row = blockIdx.x * 128;
    const float4* X4 = (const float4*)X;
    for (int i = tid; i < 128 * 16; i += 256) {
        int r = i >> 4, c = i & 15;
        int gr = base_row + r;
        float4 v = make_float4(0.f, 0.f, 0.f, 0.f);
        if (gr < n) v = X4[(size_t)gr * 16 + c];
        sX4[r * XPITCH + c] = v;
    }
    __syncthreads();

    int cg = tid % COLG;
    int rg = tid / COLG;
    float4 acc[RPT];
#pragma unroll
    for (int r = 0; r < RPT; ++r) acc[r] = make_float4(0.f, 0.f, 0.f, 0.f);

#pragma unroll
    for (int k4 = 0; k4 < 16; ++k4) {
        float4 w0 = sW4[(k4 * 4 + 0) * COLG + cg];
        float4 w1 = sW4[(k4 * 4 + 1) * COLG + cg];
        float4 w2 = sW4[(k4 * 4 + 2) * COLG + cg];
        float4 w3 = sW4[(k4 * 4 + 3) * COLG + cg];
#pragma unroll
        for (int r = 0; r < RPT; ++r) {
            float4 xv = sX4[(rg + RGS * r) * XPITCH + k4];
            acc[r].x = fmaf(xv.x, w0.x, acc[r].x);
            acc[r].y = fmaf(xv.x, w0.y, acc[r].y);
            acc[r].z = fmaf(xv.x, w0.z, acc[r].z);
            acc[r].w = fmaf(xv.x, w0.w, acc[r].w);
            acc[r].x = fmaf(xv.y, w1.x, acc[r].x);
            acc[r].y = fmaf(xv.y, w1.y, acc[r].y);
            acc[r].z = fmaf(xv.y, w1.z, acc[r].z);
            acc[r].w = fmaf(xv.y, w1.w, acc[r].w);
            acc[r].x = fmaf(xv.z, w2.x, acc[r].x);
            acc[r].y = fmaf(xv.z, w2.y, acc[r].y);
            acc[r].z = fmaf(xv.z, w2.z, acc[r].z);
            acc[r].w = fmaf(xv.z, w2.w, acc[r].w);
            acc[r].x = fmaf(xv.w, w3.x, acc[r].x);
            acc[r].y = fmaf(xv.w, w3.y, acc[r].y);
            acc[r].z = fmaf(xv.w, w3.z, acc[r].z);
            acc[r].w = fmaf(xv.w, w3.w, acc[r].w);
        }
    }

#pragma unroll
    for (int r = 0; r < RPT; ++r) {
        int grow = base_row + rg + RGS * r;
        if (grow < n) {
            float4 v = acc[r];
            if (rowscale) {
                float s = rowscale[grow];
                v.x *= s; v.y *= s; v.z *= s; v.w *= s;
            }
            if (bias) {
                float4 bb = ((const float4*)bias)[cg];
                v.x += bb.x; v.y += bb.y; v.z += bb.z; v.w += bb.w;
            }
            ((float4*)H)[(size_t)grow * COLG + cg] = v;
        }
    }
}

// ---------------- fused local-CSR + gather aggregation + epilogue ----------------
// tmp rows are pre-scaled by dinv[row]. For node v:
//   h[v] = relu(dinv[v] * (tmp[v] + sum_{e: dst=v} tmp[src_e]) + b)
__global__ void aggregate_kernel(const float* __restrict__ tmp,
                                 const unsigned int* __restrict__ binned,
                                 const int* __restrict__ gcursor,
                                 const float* __restrict__ dinv,
                                 const float* __restrict__ b,
                                 float* __restrict__ h) {
    __shared__ unsigned int eLDS[CAP];
    __shared__ unsigned int srcs[CAP];
    __shared__ unsigned int counts[NODES_PER_BIN];
    __shared__ unsigned int scan[NODES_PER_BIN];
    __shared__ unsigned int offs[NODES_PER_BIN];
    __shared__ unsigned int cur[NODES_PER_BIN];
    int bin = blockIdx.x;
    int t = threadIdx.x;
    int nb = gcursor[bin];
    const unsigned int* eb = binned + (size_t)bin * CAP;

    if (t < NODES_PER_BIN) counts[t] = 0;
    __syncthreads();
    for (int i = t; i < nb; i += 256) {
        unsigned int p = eb[i];
        eLDS[i] = p;
        atomicAdd(&counts[p >> 17], 1u);
    }
    __syncthreads();
    if (t < NODES_PER_BIN) scan[t] = counts[t];
    __syncthreads();
    for (int step = 1; step < NODES_PER_BIN; step <<= 1) {
        unsigned int v = 0;
        if (t < NODES_PER_BIN && t >= step) v = scan[t - step];
        __syncthreads();
        if (t < NODES_PER_BIN) scan[t] += v;
        __syncthreads();
    }
    if (t < NODES_PER_BIN) {
        offs[t] = scan[t] - counts[t];
        cur[t] = 0;
    }
    __syncthreads();
    for (int i = t; i < nb; i += 256) {
        unsigned int p = eLDS[i];
        unsigned int l = p >> 17;
        unsigned int pos = offs[l] + atomicAdd(&cur[l], 1u);
        srcs[pos] = p & 0x1FFFFu;
    }
    __syncthreads();
    int q = t & 15;
    int lnode0 = t >> 4;
    const float4* tmp4 = (const float4*)tmp;
    float4 bb = ((const float4*)b)[q];
#pragma unroll
    for (int g = 0; g < 4; ++g) {
        int ln = g * 16 + lnode0;
        int node = bin * NODES_PER_BIN + ln;
        if (node < N_NODES) {
            int deg = (int)counts[ln];
            int beg = (int)offs[ln];
            float4 acc = tmp4[(size_t)node * 16 + q];
            float4 acc2 = make_float4(0.f, 0.f, 0.f, 0.f);
            int e = 0;
            for (; e + 1 < deg; e += 2) {
                unsigned int s0 = srcs[beg + e];
                unsigned int s1 = srcs[beg + e + 1];
                float4 m0 = tmp4[(size_t)s0 * 16 + q];
                float4 m1 = tmp4[(size_t)s1 * 16 + q];
                acc.x += m0.x; acc.y += m0.y; acc.z += m0.z; acc.w += m0.w;
                acc2.x += m1.x; acc2.y += m1.y; acc2.z += m1.z; acc2.w += m1.w;
            }
            if (e < deg) {
                unsigned int s0 = srcs[beg + e];
                float4 m0 = tmp4[(size_t)s0 * 16 + q];
                acc.x += m0.x; acc.y += m0.y; acc.z += m0.z; acc.w += m0.w;
            }
            acc.x += acc2.x; acc.y += acc2.y; acc.z += acc2.z; acc.w += acc2.w;
            float dv = dinv[node];
            float4 r;
            r.x = fmaxf(fmaf(dv, acc.x, bb.x), 0.0f);
            r.y = fmaxf(fmaf(dv, acc.y, bb.y), 0.0f);
            r.z = fmaxf(fmaf(dv, acc.z, bb.z), 0.0f);
            r.w = fmaxf(fmaf(dv, acc.w, bb.w), 0.0f);
            ((float4*)(h + (size_t)node * 64))[q] = r;
        }
    }
}

extern "C" void kernel_launch(void* const* d_in, const int* in_sizes, int n_in,
                              void* d_out, int out_size, void* d_ws, size_t ws_size,
                              hipStream_t stream) {
    const float* x  = (const float*)d_in[0];
    const int*   ei = (const int*)d_in[1];   // [2*E]: src row, then dst row
    const float* W1 = (const float*)d_in[2];
    const float* b1 = (const float*)d_in[3];
    const float* W2 = (const float*)d_in[4];
    const float* b2 = (const float*)d_in[5];
    const float* Wl = (const float*)d_in[6];
    const float* bl = (const float*)d_in[7];
    float* out = (float*)d_out;

    const int N = N_NODES;
    const int E = N_EDGES;
    const int* src = ei;
    const int* dst = ei + E;

    // workspace: gcursor[NBINS] i32 | dinv[N] f32 | binned[NBINS*CAP] u32 | tmp[N*64] f32 | h[N*64] f32
    char* ws = (char*)d_ws;
    size_t off = 0;
    auto align = [](size_t v) { return (v + 511) & ~(size_t)511; };
    int* gcursor         = (int*)(ws + off);          off = align(off + (size_t)NBINS * 4);
    float* dinv          = (float*)(ws + off);        off = align(off + (size_t)N * 4);
    unsigned int* binned = (unsigned int*)(ws + off); off = align(off + (size_t)NBINS * CAP * 4);
    float* tmp           = (float*)(ws + off);        off = align(off + (size_t)N * 64 * 4);
    float* h             = (float*)(ws + off);        off = align(off + (size_t)N * 64 * 4);
    (void)ws_size;

    const int NBLK_GEMM = (N + 127) / 128;  // 782

    // ---- binned COO build ----
    zero_int_kernel<<<(NBINS + 255) / 256, 256, 0, stream>>>(gcursor, NBINS);
    binning_kernel<<<NBLK_BIN, 256, 0, stream>>>(src, dst, gcursor, binned, E);
    dinv_kernel<<<NBINS, 256, 0, stream>>>(binned, gcursor, dinv);

    // ---- layer 1: tmp = dinv * (x @ W1); h = relu(dinv * gather(tmp) + b1) ----
    gemm_kernel<64><<<NBLK_GEMM, 256, 0, stream>>>(x, W1, nullptr, dinv, tmp, N);
    aggregate_kernel<<<NBINS, 256, 0, stream>>>(tmp, binned, gcursor, dinv, b1, h);

    // ---- layer 2 ----
    gemm_kernel<64><<<NBLK_GEMM, 256, 0, stream>>>(h, W2, nullptr, dinv, tmp, N);
    aggregate_kernel<<<NBINS, 256, 0, stream>>>(tmp, binned, gcursor, dinv, b2, h);

    // ---- head: out = h @ Wl + bl ----
    gemm_kernel<32><<<NBLK_GEMM, 256, 0, stream>>>(h, Wl, bl, nullptr, out, N);
}

// Round 5
// 261.663 us; speedup vs baseline: 1.7811x; 1.7811x over previous
//
#include <hip/hip_runtime.h>

#define N_NODES 100000
#define N_EDGES 1200000

#define BIN_SHIFT 6
#define NODES_PER_BIN 64                       // 1 << BIN_SHIFT
#define NBINS ((N_NODES + NODES_PER_BIN - 1) >> BIN_SHIFT)   // 1563
#define CAP 1024                               // max edges per bucket (mean 768)
#define EPB 8192                               // edges per binning block
#define NBLK_BIN ((N_EDGES + EPB - 1) / EPB)   // 147

// ---------------- zero int ----------------
__global__ void zero_int_kernel(int* __restrict__ p, int n) {
    int i = blockIdx.x * blockDim.x + threadIdx.x;
    if (i < n) p[i] = 0;
}

// ---------------- binning: edges -> fixed-stride bucket regions ----------------
// packed word: src (bits 0..16) | (dst & 63) << 17
__global__ void binning_kernel(const int* __restrict__ src, const int* __restrict__ dst,
                               int* __restrict__ gcursor, unsigned int* __restrict__ binned,
                               int E) {
    __shared__ unsigned int stage[EPB];      // 32 KB
    __shared__ unsigned short sbin[EPB];     // 16 KB
    __shared__ unsigned int hist[NBINS];     // ~6.3 KB
    int t = threadIdx.x;
    int e_base = blockIdx.x * EPB;

    for (int b = t; b < NBINS; b += 256) hist[b] = 0;
    __syncthreads();

#pragma unroll
    for (int j = 0; j < EPB / 256; ++j) {
        int idx = e_base + t + j * 256;
        if (idx < E) {
            int s = src[idx];
            int d = dst[idx];
            unsigned int bin = (unsigned int)d >> BIN_SHIFT;
            unsigned int p = (unsigned int)s | (((unsigned int)d & 63u) << 17);
            stage[t + j * 256] = p;
            sbin[t + j * 256] = (unsigned short)bin;
            atomicAdd(&hist[bin], 1u);
        }
    }
    __syncthreads();

    for (int b = t; b < NBINS; b += 256) {
        unsigned int c = hist[b];
        if (c) hist[b] = (unsigned int)(b * CAP) + (unsigned int)atomicAdd(&gcursor[b], (int)c);
    }
    __syncthreads();

#pragma unroll
    for (int j = 0; j < EPB / 256; ++j) {
        int idx = e_base + t + j * 256;
        if (idx < E) {
            unsigned int bin = sbin[t + j * 256];
            unsigned int pos = atomicAdd(&hist[bin], 1u);
            binned[pos] = stage[t + j * 256];
        }
    }
}

// ---------------- dinv: per-bucket local degree count -> rsqrt(deg+1) ----------------
__global__ void dinv_kernel(const unsigned int* __restrict__ binned,
                            const int* __restrict__ gcursor,
                            float* __restrict__ dinv) {
    __shared__ unsigned int counts[NODES_PER_BIN];
    int bin = blockIdx.x;
    int t = threadIdx.x;
    if (t < NODES_PER_BIN) counts[t] = 0;
    __syncthreads();
    int nb = gcursor[bin];
    const unsigned int* eb = binned + (size_t)bin * CAP;
    for (int i = t; i < nb; i += 256) atomicAdd(&counts[eb[i] >> 17], 1u);
    __syncthreads();
    if (t < NODES_PER_BIN) {
        int node = bin * NODES_PER_BIN + t;
        if (node < N_NODES) dinv[node] = rsqrtf((float)(counts[t] + 1u));
    }
}

// ---------------- register-tiled skinny GEMM (64 rows/block) ----------------
// H[n,DOUT] = rowscale[r] * (X[n,64] @ W[64,DOUT]) (+bias)
// 256 threads. Thread (rg,cg): rows rg+RGS*r (r<RPT), cols 4*cg..4*cg+3.
// All LDS traffic is ds_read_b128; sX padded to 17 float4/row.
// __launch_bounds__(256,4) caps VGPRs at 128 (min usage ~90) -> no spill;
// 4 blocks/CU also matches the 33.4 KB LDS limit.
template<int DOUT>
__global__ __launch_bounds__(256, 4) void gemm_kernel(const float* __restrict__ X,
                                                      const float* __restrict__ W,
                                                      const float* __restrict__ bias,
                                                      const float* __restrict__ rowscale,
                                                      float* __restrict__ H, int n) {
    constexpr int COLG = DOUT / 4;       // 16 (d64) or 8 (d32)
    constexpr int RGS  = 256 / COLG;     // 16 or 32
    constexpr int RPT  = 64 / RGS;       // 4 or 2
    constexpr int XPITCH = 17;           // float4 pitch
    __shared__ float4 sW4[64 * COLG];
    __shared__ float4 sX4[64 * XPITCH];
    int tid = threadIdx.x;

    for (int i = tid; i < 64 * COLG; i += 256) sW4[i] = ((const float4*)W)[i];

    int base_row = blockIdx.x * 64;
    const float4* X4 = (const float4*)X;
    for (int i = tid; i < 64 * 16; i += 256) {
        int r = i >> 4, c = i & 15;
        int gr = base_row + r;
        float4 v = make_float4(0.f, 0.f, 0.f, 0.f);
        if (gr < n) v = X4[(size_t)gr * 16 + c];
        sX4[r * XPITCH + c] = v;
    }
    __syncthreads();

    int cg = tid % COLG;
    int rg = tid / COLG;
    float4 acc[RPT];
#pragma unroll
    for (int r = 0; r < RPT; ++r) acc[r] = make_float4(0.f, 0.f, 0.f, 0.f);

#pragma unroll 2
    for (int k4 = 0; k4 < 16; ++k4) {
        float4 xv[RPT];
#pragma unroll
        for (int r = 0; r < RPT; ++r) xv[r] = sX4[(rg + RGS * r) * XPITCH + k4];
#pragma unroll
        for (int kk = 0; kk < 4; ++kk) {
            float4 w = sW4[(k4 * 4 + kk) * COLG + cg];
#pragma unroll
            for (int r = 0; r < RPT; ++r) {
                float xs = (kk == 0) ? xv[r].x : (kk == 1) ? xv[r].y : (kk == 2) ? xv[r].z : xv[r].w;
                acc[r].x = fmaf(xs, w.x, acc[r].x);
                acc[r].y = fmaf(xs, w.y, acc[r].y);
                acc[r].z = fmaf(xs, w.z, acc[r].z);
                acc[r].w = fmaf(xs, w.w, acc[r].w);
            }
        }
    }

#pragma unroll
    for (int r = 0; r < RPT; ++r) {
        int grow = base_row + rg + RGS * r;
        if (grow < n) {
            float4 v = acc[r];
            if (rowscale) {
                float s = rowscale[grow];
                v.x *= s; v.y *= s; v.z *= s; v.w *= s;
            }
            if (bias) {
                float4 bb = ((const float4*)bias)[cg];
                v.x += bb.x; v.y += bb.y; v.z += bb.z; v.w += bb.w;
            }
            ((float4*)H)[(size_t)grow * COLG + cg] = v;
        }
    }
}

// ---------------- fused local-CSR + gather aggregation + epilogue ----------------
// tmp rows are pre-scaled by dinv[row]. For node v:
//   h[v] = relu(dinv[v] * (tmp[v] + sum_{e: dst=v} tmp[src_e]) + b)
__global__ void aggregate_kernel(const float* __restrict__ tmp,
                                 const unsigned int* __restrict__ binned,
                                 const int* __restrict__ gcursor,
                                 const float* __restrict__ dinv,
                                 const float* __restrict__ b,
                                 float* __restrict__ h) {
    __shared__ unsigned int eLDS[CAP];
    __shared__ unsigned int srcs[CAP];
    __shared__ unsigned int counts[NODES_PER_BIN];
    __shared__ unsigned int scan[NODES_PER_BIN];
    __shared__ unsigned int offs[NODES_PER_BIN];
    __shared__ unsigned int cur[NODES_PER_BIN];
    int bin = blockIdx.x;
    int t = threadIdx.x;
    int nb = gcursor[bin];
    const unsigned int* eb = binned + (size_t)bin * CAP;

    if (t < NODES_PER_BIN) counts[t] = 0;
    __syncthreads();
    for (int i = t; i < nb; i += 256) {
        unsigned int p = eb[i];
        eLDS[i] = p;
        atomicAdd(&counts[p >> 17], 1u);
    }
    __syncthreads();
    if (t < NODES_PER_BIN) scan[t] = counts[t];
    __syncthreads();
    for (int step = 1; step < NODES_PER_BIN; step <<= 1) {
        unsigned int v = 0;
        if (t < NODES_PER_BIN && t >= step) v = scan[t - step];
        __syncthreads();
        if (t < NODES_PER_BIN) scan[t] += v;
        __syncthreads();
    }
    if (t < NODES_PER_BIN) {
        offs[t] = scan[t] - counts[t];
        cur[t] = 0;
    }
    __syncthreads();
    for (int i = t; i < nb; i += 256) {
        unsigned int p = eLDS[i];
        unsigned int l = p >> 17;
        unsigned int pos = offs[l] + atomicAdd(&cur[l], 1u);
        srcs[pos] = p & 0x1FFFFu;
    }
    __syncthreads();
    int q = t & 15;
    int lnode0 = t >> 4;
    const float4* tmp4 = (const float4*)tmp;
    float4 bb = ((const float4*)b)[q];
#pragma unroll
    for (int g = 0; g < 4; ++g) {
        int ln = g * 16 + lnode0;
        int node = bin * NODES_PER_BIN + ln;
        if (node < N_NODES) {
            int deg = (int)counts[ln];
            int beg = (int)offs[ln];
            float4 acc = tmp4[(size_t)node * 16 + q];
            float4 acc2 = make_float4(0.f, 0.f, 0.f, 0.f);
            int e = 0;
            for (; e + 1 < deg; e += 2) {
                unsigned int s0 = srcs[beg + e];
                unsigned int s1 = srcs[beg + e + 1];
                float4 m0 = tmp4[(size_t)s0 * 16 + q];
                float4 m1 = tmp4[(size_t)s1 * 16 + q];
                acc.x += m0.x; acc.y += m0.y; acc.z += m0.z; acc.w += m0.w;
                acc2.x += m1.x; acc2.y += m1.y; acc2.z += m1.z; acc2.w += m1.w;
            }
            if (e < deg) {
                unsigned int s0 = srcs[beg + e];
                float4 m0 = tmp4[(size_t)s0 * 16 + q];
                acc.x += m0.x; acc.y += m0.y; acc.z += m0.z; acc.w += m0.w;
            }
            acc.x += acc2.x; acc.y += acc2.y; acc.z += acc2.z; acc.w += acc2.w;
            float dv = dinv[node];
            float4 r;
            r.x = fmaxf(fmaf(dv, acc.x, bb.x), 0.0f);
            r.y = fmaxf(fmaf(dv, acc.y, bb.y), 0.0f);
            r.z = fmaxf(fmaf(dv, acc.z, bb.z), 0.0f);
            r.w = fmaxf(fmaf(dv, acc.w, bb.w), 0.0f);
            ((float4*)(h + (size_t)node * 64))[q] = r;
        }
    }
}

extern "C" void kernel_launch(void* const* d_in, const int* in_sizes, int n_in,
                              void* d_out, int out_size, void* d_ws, size_t ws_size,
                              hipStream_t stream) {
    const float* x  = (const float*)d_in[0];
    const int*   ei = (const int*)d_in[1];   // [2*E]: src row, then dst row
    const float* W1 = (const float*)d_in[2];
    const float* b1 = (const float*)d_in[3];
    const float* W2 = (const float*)d_in[4];
    const float* b2 = (const float*)d_in[5];
    const float* Wl = (const float*)d_in[6];
    const float* bl = (const float*)d_in[7];
    float* out = (float*)d_out;

    const int N = N_NODES;
    const int E = N_EDGES;
    const int* src = ei;
    const int* dst = ei + E;

    // workspace: gcursor[NBINS] i32 | dinv[N] f32 | binned[NBINS*CAP] u32 | tmp[N*64] f32 | h[N*64] f32
    char* ws = (char*)d_ws;
    size_t off = 0;
    auto align = [](size_t v) { return (v + 511) & ~(size_t)511; };
    int* gcursor         = (int*)(ws + off);          off = align(off + (size_t)NBINS * 4);
    float* dinv          = (float*)(ws + off);        off = align(off + (size_t)N * 4);
    unsigned int* binned = (unsigned int*)(ws + off); off = align(off + (size_t)NBINS * CAP * 4);
    float* tmp           = (float*)(ws + off);        off = align(off + (size_t)N * 64 * 4);
    float* h             = (float*)(ws + off);        off = align(off + (size_t)N * 64 * 4);
    (void)ws_size;

    const int NBLK_GEMM = (N + 63) / 64;  // 1563

    // ---- binned COO build ----
    zero_int_kernel<<<(NBINS + 255) / 256, 256, 0, stream>>>(gcursor, NBINS);
    binning_kernel<<<NBLK_BIN, 256, 0, stream>>>(src, dst, gcursor, binned, E);
    dinv_kernel<<<NBINS, 256, 0, stream>>>(binned, gcursor, dinv);

    // ---- layer 1: tmp = dinv * (x @ W1); h = relu(dinv * gather(tmp) + b1) ----
    gemm_kernel<64><<<NBLK_GEMM, 256, 0, stream>>>(x, W1, nullptr, dinv, tmp, N);
    aggregate_kernel<<<NBINS, 256, 0, stream>>>(tmp, binned, gcursor, dinv, b1, h);

    // ---- layer 2 ----
    gemm_kernel<64><<<NBLK_GEMM, 256, 0, stream>>>(h, W2, nullptr, dinv, tmp, N);
    aggregate_kernel<<<NBINS, 256, 0, stream>>>(tmp, binned, gcursor, dinv, b2, h);

    // ---- head: out = h @ Wl + bl ----
    gemm_kernel<32><<<NBLK_GEMM, 256, 0, stream>>>(h, Wl, bl, nullptr, out, N);
}

// Round 6
// 213.786 us; speedup vs baseline: 2.1799x; 1.2239x over previous
//
#include <hip/hip_runtime.h>
#include <hip/hip_fp16.h>

#define N_NODES 100000
#define N_EDGES 1200000

#define BIN_SHIFT 6
#define NODES_PER_BIN 64                       // 1 << BIN_SHIFT
#define NBINS ((N_NODES + NODES_PER_BIN - 1) >> BIN_SHIFT)   // 1563
#define CAP 1024                               // max edges per bucket (mean 768)
#define EPB 8192                               // edges per binning block
#define NBLK_BIN ((N_EDGES + EPB - 1) / EPB)   // 147

// ---------------- zero int ----------------
__global__ void zero_int_kernel(int* __restrict__ p, int n) {
    int i = blockIdx.x * blockDim.x + threadIdx.x;
    if (i < n) p[i] = 0;
}

// ---------------- binning: edges -> fixed-stride bucket regions ----------------
// packed word: src (bits 0..16) | (dst & 63) << 17
__global__ void binning_kernel(const int* __restrict__ src, const int* __restrict__ dst,
                               int* __restrict__ gcursor, unsigned int* __restrict__ binned,
                               int E) {
    __shared__ unsigned int stage[EPB];      // 32 KB
    __shared__ unsigned short sbin[EPB];     // 16 KB
    __shared__ unsigned int hist[NBINS];     // ~6.3 KB
    int t = threadIdx.x;
    int e_base = blockIdx.x * EPB;

    for (int b = t; b < NBINS; b += 256) hist[b] = 0;
    __syncthreads();

#pragma unroll
    for (int j = 0; j < EPB / 256; ++j) {
        int idx = e_base + t + j * 256;
        if (idx < E) {
            int s = src[idx];
            int d = dst[idx];
            unsigned int bin = (unsigned int)d >> BIN_SHIFT;
            unsigned int p = (unsigned int)s | (((unsigned int)d & 63u) << 17);
            stage[t + j * 256] = p;
            sbin[t + j * 256] = (unsigned short)bin;
            atomicAdd(&hist[bin], 1u);
        }
    }
    __syncthreads();

    for (int b = t; b < NBINS; b += 256) {
        unsigned int c = hist[b];
        if (c) hist[b] = (unsigned int)(b * CAP) + (unsigned int)atomicAdd(&gcursor[b], (int)c);
    }
    __syncthreads();

#pragma unroll
    for (int j = 0; j < EPB / 256; ++j) {
        int idx = e_base + t + j * 256;
        if (idx < E) {
            unsigned int bin = sbin[t + j * 256];
            unsigned int pos = atomicAdd(&hist[bin], 1u);
            binned[pos] = stage[t + j * 256];
        }
    }
}

// ---------------- dinv: per-bucket local degree count -> rsqrt(deg+1) ----------------
__global__ void dinv_kernel(const unsigned int* __restrict__ binned,
                            const int* __restrict__ gcursor,
                            float* __restrict__ dinv) {
    __shared__ unsigned int counts[NODES_PER_BIN];
    int bin = blockIdx.x;
    int t = threadIdx.x;
    if (t < NODES_PER_BIN) counts[t] = 0;
    __syncthreads();
    int nb = gcursor[bin];
    const unsigned int* eb = binned + (size_t)bin * CAP;
    for (int i = t; i < nb; i += 256) atomicAdd(&counts[eb[i] >> 17], 1u);
    __syncthreads();
    if (t < NODES_PER_BIN) {
        int node = bin * NODES_PER_BIN + t;
        if (node < N_NODES) dinv[node] = rsqrtf((float)(counts[t] + 1u));
    }
}

// ---------------- register-tiled skinny GEMM (64 rows/block) ----------------
// H[n,DOUT] = rowscale[r] * (X[n,64] @ W[64,DOUT]) (+bias)
// HALF_OUT: write fp16 (packed v_cvt_pkrtz); else fp32.
template<int DOUT, bool HALF_OUT>
__global__ __launch_bounds__(256, 4) void gemm_kernel(const float* __restrict__ X,
                                                      const float* __restrict__ W,
                                                      const float* __restrict__ bias,
                                                      const float* __restrict__ rowscale,
                                                      void* __restrict__ Hout, int n) {
    constexpr int COLG = DOUT / 4;       // 16 (d64) or 8 (d32)
    constexpr int RGS  = 256 / COLG;     // 16 or 32
    constexpr int RPT  = 64 / RGS;       // 4 or 2
    constexpr int XPITCH = 17;           // float4 pitch
    __shared__ float4 sW4[64 * COLG];
    __shared__ float4 sX4[64 * XPITCH];
    int tid = threadIdx.x;

    for (int i = tid; i < 64 * COLG; i += 256) sW4[i] = ((const float4*)W)[i];

    int base_row = blockIdx.x * 64;
    const float4* X4 = (const float4*)X;
    for (int i = tid; i < 64 * 16; i += 256) {
        int r = i >> 4, c = i & 15;
        int gr = base_row + r;
        float4 v = make_float4(0.f, 0.f, 0.f, 0.f);
        if (gr < n) v = X4[(size_t)gr * 16 + c];
        sX4[r * XPITCH + c] = v;
    }
    __syncthreads();

    int cg = tid % COLG;
    int rg = tid / COLG;
    float4 acc[RPT];
#pragma unroll
    for (int r = 0; r < RPT; ++r) acc[r] = make_float4(0.f, 0.f, 0.f, 0.f);

#pragma unroll 2
    for (int k4 = 0; k4 < 16; ++k4) {
        float4 xv[RPT];
#pragma unroll
        for (int r = 0; r < RPT; ++r) xv[r] = sX4[(rg + RGS * r) * XPITCH + k4];
#pragma unroll
        for (int kk = 0; kk < 4; ++kk) {
            float4 w = sW4[(k4 * 4 + kk) * COLG + cg];
#pragma unroll
            for (int r = 0; r < RPT; ++r) {
                float xs = (kk == 0) ? xv[r].x : (kk == 1) ? xv[r].y : (kk == 2) ? xv[r].z : xv[r].w;
                acc[r].x = fmaf(xs, w.x, acc[r].x);
                acc[r].y = fmaf(xs, w.y, acc[r].y);
                acc[r].z = fmaf(xs, w.z, acc[r].z);
                acc[r].w = fmaf(xs, w.w, acc[r].w);
            }
        }
    }

#pragma unroll
    for (int r = 0; r < RPT; ++r) {
        int grow = base_row + rg + RGS * r;
        if (grow < n) {
            float4 v = acc[r];
            if (rowscale) {
                float s = rowscale[grow];
                v.x *= s; v.y *= s; v.z *= s; v.w *= s;
            }
            if (bias) {
                float4 bb = ((const float4*)bias)[cg];
                v.x += bb.x; v.y += bb.y; v.z += bb.z; v.w += bb.w;
            }
            if (HALF_OUT) {
                __half2* H2 = (__half2*)Hout;
                size_t idx = (size_t)grow * (DOUT / 2) + 2 * cg;
                H2[idx]     = __floats2half2_rn(v.x, v.y);
                H2[idx + 1] = __floats2half2_rn(v.z, v.w);
            } else {
                ((float4*)Hout)[(size_t)grow * COLG + cg] = v;
            }
        }
    }
}

// ---------------- fused local-CSR + gather aggregation + epilogue ----------------
// tmp (fp16) rows are pre-scaled by dinv[row]. For node v:
//   h[v] = relu(dinv[v] * (tmp[v] + sum_{e: dst=v} tmp[src_e]) + b)
// 8 threads/node, 16 B (8 halves) per thread -> one 128 B line per edge.
__global__ void aggregate_kernel(const __half* __restrict__ tmp,
                                 const unsigned int* __restrict__ binned,
                                 const int* __restrict__ gcursor,
                                 const float* __restrict__ dinv,
                                 const float* __restrict__ b,
                                 float* __restrict__ h) {
    __shared__ unsigned int eLDS[CAP];
    __shared__ unsigned int srcs[CAP];
    __shared__ unsigned int counts[NODES_PER_BIN];
    __shared__ unsigned int scan[NODES_PER_BIN];
    __shared__ unsigned int offs[NODES_PER_BIN];
    __shared__ unsigned int cur[NODES_PER_BIN];
    int bin = blockIdx.x;
    int t = threadIdx.x;
    int nb = gcursor[bin];
    const unsigned int* eb = binned + (size_t)bin * CAP;

    if (t < NODES_PER_BIN) counts[t] = 0;
    __syncthreads();
    for (int i = t; i < nb; i += 256) {
        unsigned int p = eb[i];
        eLDS[i] = p;
        atomicAdd(&counts[p >> 17], 1u);
    }
    __syncthreads();
    if (t < NODES_PER_BIN) scan[t] = counts[t];
    __syncthreads();
    for (int step = 1; step < NODES_PER_BIN; step <<= 1) {
        unsigned int v = 0;
        if (t < NODES_PER_BIN && t >= step) v = scan[t - step];
        __syncthreads();
        if (t < NODES_PER_BIN) scan[t] += v;
        __syncthreads();
    }
    if (t < NODES_PER_BIN) {
        offs[t] = scan[t] - counts[t];
        cur[t] = 0;
    }
    __syncthreads();
    for (int i = t; i < nb; i += 256) {
        unsigned int p = eLDS[i];
        unsigned int l = p >> 17;
        unsigned int pos = offs[l] + atomicAdd(&cur[l], 1u);
        srcs[pos] = p & 0x1FFFFu;
    }
    __syncthreads();

    int oct = t & 7;            // 16 B slice within the 128 B row
    int lnode0 = t >> 3;        // 0..31
    const uint4* tmp16 = (const uint4*)tmp;   // row = 8 uint4
    float bb[8];
    {
        const float4 b0 = ((const float4*)b)[oct * 2];
        const float4 b1 = ((const float4*)b)[oct * 2 + 1];
        bb[0] = b0.x; bb[1] = b0.y; bb[2] = b0.z; bb[3] = b0.w;
        bb[4] = b1.x; bb[5] = b1.y; bb[6] = b1.z; bb[7] = b1.w;
    }

#pragma unroll
    for (int g = 0; g < 2; ++g) {
        int ln = g * 32 + lnode0;
        int node = bin * NODES_PER_BIN + ln;
        if (node < N_NODES) {
            int deg = (int)counts[ln];
            int beg = (int)offs[ln];
            float acc[8];
            {
                uint4 raw = tmp16[(size_t)node * 8 + oct];   // self-loop term
                const __half2* hp = (const __half2*)&raw;
#pragma unroll
                for (int j = 0; j < 4; ++j) {
                    float2 f = __half22float2(hp[j]);
                    acc[2 * j] = f.x; acc[2 * j + 1] = f.y;
                }
            }
            int e = 0;
            for (; e + 1 < deg; e += 2) {
                unsigned int s0 = srcs[beg + e];
                unsigned int s1 = srcs[beg + e + 1];
                uint4 r0 = tmp16[(size_t)s0 * 8 + oct];
                uint4 r1 = tmp16[(size_t)s1 * 8 + oct];
                const __half2* h0 = (const __half2*)&r0;
                const __half2* h1 = (const __half2*)&r1;
#pragma unroll
                for (int j = 0; j < 4; ++j) {
                    float2 f0 = __half22float2(h0[j]);
                    float2 f1 = __half22float2(h1[j]);
                    acc[2 * j]     += f0.x + f1.x;
                    acc[2 * j + 1] += f0.y + f1.y;
                }
            }
            if (e < deg) {
                unsigned int s0 = srcs[beg + e];
                uint4 r0 = tmp16[(size_t)s0 * 8 + oct];
                const __half2* h0 = (const __half2*)&r0;
#pragma unroll
                for (int j = 0; j < 4; ++j) {
                    float2 f0 = __half22float2(h0[j]);
                    acc[2 * j]     += f0.x;
                    acc[2 * j + 1] += f0.y;
                }
            }
            float dv = dinv[node];
            float4 o0, o1;
            o0.x = fmaxf(fmaf(dv, acc[0], bb[0]), 0.0f);
            o0.y = fmaxf(fmaf(dv, acc[1], bb[1]), 0.0f);
            o0.z = fmaxf(fmaf(dv, acc[2], bb[2]), 0.0f);
            o0.w = fmaxf(fmaf(dv, acc[3], bb[3]), 0.0f);
            o1.x = fmaxf(fmaf(dv, acc[4], bb[4]), 0.0f);
            o1.y = fmaxf(fmaf(dv, acc[5], bb[5]), 0.0f);
            o1.z = fmaxf(fmaf(dv, acc[6], bb[6]), 0.0f);
            o1.w = fmaxf(fmaf(dv, acc[7], bb[7]), 0.0f);
            float4* hv = (float4*)(h + (size_t)node * 64 + oct * 8);
            hv[0] = o0;
            hv[1] = o1;
        }
    }
}

extern "C" void kernel_launch(void* const* d_in, const int* in_sizes, int n_in,
                              void* d_out, int out_size, void* d_ws, size_t ws_size,
                              hipStream_t stream) {
    const float* x  = (const float*)d_in[0];
    const int*   ei = (const int*)d_in[1];   // [2*E]: src row, then dst row
    const float* W1 = (const float*)d_in[2];
    const float* b1 = (const float*)d_in[3];
    const float* W2 = (const float*)d_in[4];
    const float* b2 = (const float*)d_in[5];
    const float* Wl = (const float*)d_in[6];
    const float* bl = (const float*)d_in[7];
    float* out = (float*)d_out;

    const int N = N_NODES;
    const int E = N_EDGES;
    const int* src = ei;
    const int* dst = ei + E;

    // workspace: gcursor[NBINS] i32 | dinv[N] f32 | binned[NBINS*CAP] u32 | tmp[N*64] f16 | h[N*64] f32
    char* ws = (char*)d_ws;
    size_t off = 0;
    auto align = [](size_t v) { return (v + 511) & ~(size_t)511; };
    int* gcursor         = (int*)(ws + off);          off = align(off + (size_t)NBINS * 4);
    float* dinv          = (float*)(ws + off);        off = align(off + (size_t)N * 4);
    unsigned int* binned = (unsigned int*)(ws + off); off = align(off + (size_t)NBINS * CAP * 4);
    __half* tmp          = (__half*)(ws + off);       off = align(off + (size_t)N * 64 * 2);
    float* h             = (float*)(ws + off);        off = align(off + (size_t)N * 64 * 4);
    (void)ws_size;

    const int NBLK_GEMM = (N + 63) / 64;  // 1563

    // ---- binned COO build ----
    zero_int_kernel<<<(NBINS + 255) / 256, 256, 0, stream>>>(gcursor, NBINS);
    binning_kernel<<<NBLK_BIN, 256, 0, stream>>>(src, dst, gcursor, binned, E);
    dinv_kernel<<<NBINS, 256, 0, stream>>>(binned, gcursor, dinv);

    // ---- layer 1: tmp = fp16(dinv * (x @ W1)); h = relu(dinv * gather(tmp) + b1) ----
    gemm_kernel<64, true><<<NBLK_GEMM, 256, 0, stream>>>(x, W1, nullptr, dinv, tmp, N);
    aggregate_kernel<<<NBINS, 256, 0, stream>>>(tmp, binned, gcursor, dinv, b1, h);

    // ---- layer 2 ----
    gemm_kernel<64, true><<<NBLK_GEMM, 256, 0, stream>>>(h, W2, nullptr, dinv, tmp, N);
    aggregate_kernel<<<NBINS, 256, 0, stream>>>(tmp, binned, gcursor, dinv, b2, h);

    // ---- head: out = h @ Wl + bl ----
    gemm_kernel<32, false><<<NBLK_GEMM, 256, 0, stream>>>(h, Wl, bl, nullptr, out, N);
}